// Round 16
// baseline (161.795 us; speedup 1.0000x reference)
//
#include <hip/hip_runtime.h>

// VQ-VAE VectorQuantizer forward, fp32, MI355X.
// B=64, C=D=64, H=W=32 -> N=65536 pixels, K=1024 codes.
// Outputs (flat concat): [0] loss, [1..4194305) quantized BCHW, [4194305..) indices (as float)
//
// R16: (a) cleanup parallelized — R15's 76us was 256 block-serial queues at
// 7% occupancy. Now: compact flagged pixels to a list (ballot + wave prefix +
// 1 atomicAdd/wave; list order nondet but per-pixel output independent ->
// deterministic result), then 2048 blocks grid-stride the list, one
// block-cooperative exact solve per pixel (body identical to R14/R15).
// (b) gemm: 2 code-tiles per barrier (32 iters), double-buffered tile-pairs
// (btile[2][2][4096], 37KB LDS, still 4 blocks/CU) — halves barrier count.
// MARGIN 8e-5 (R14/R15-validated). Exact-path arithmetic BIT-IDENTICAL to
// R0-R15 (passed, absmax 3.8e-6): pairwise-8 x_sq (contract off),
// d-ascending fp32 FMA chain, (xsq-2d)+esq, ascending-k strict-<.

#define KCODES 1024
#define DDIM   64
#define NPIX   65536
#define QELEMS 4194304
#define IDX_OFF (1 + QELEMS)
#define MARGIN 8e-5f
#define NPAIR  32          // 64 tiles / 2 per iteration

typedef __attribute__((ext_vector_type(8))) short bf16x8;
typedef __attribute__((ext_vector_type(4))) float f32x4;

static __device__ __forceinline__ unsigned short f2bf(float f) {
    unsigned int u = __float_as_uint(f);
    unsigned int r = (u + 0x7FFFu + ((u >> 16) & 1u)) >> 16;   // RNE
    return (unsigned short)r;
}
static __device__ __forceinline__ float bf2f(unsigned short h) {
    return __uint_as_float(((unsigned int)h) << 16);
}

// ---------------- e prep: esq (EXACT numpy pairwise-8) + bf16 split + counter zero ----------------
__global__ void __launch_bounds__(256) esplit_kernel(const float* __restrict__ e,
                                                     float* __restrict__ esq,
                                                     unsigned short* __restrict__ Eh,
                                                     unsigned short* __restrict__ El,
                                                     int* __restrict__ count) {
    if (blockIdx.x == 0 && threadIdx.x == 0) *count = 0;
    int k = blockIdx.x * 256 + threadIdx.x;
    if (k >= KCODES) return;
    const float* row = e + k * DDIM;
    {
#pragma clang fp contract(off)
        float r[8];
#pragma unroll
        for (int j = 0; j < 8; ++j) r[j] = row[j] * row[j];
#pragma unroll
        for (int i = 1; i < 8; ++i) {
#pragma unroll
            for (int j = 0; j < 8; ++j) { float v = row[i * 8 + j]; r[j] += v * v; }
        }
        esq[k] = ((r[0] + r[1]) + (r[2] + r[3])) + ((r[4] + r[5]) + (r[6] + r[7]));
    }
#pragma unroll
    for (int d = 0; d < DDIM; ++d) {
        float v = row[d];
        unsigned short h = f2bf(v);
        Eh[k * DDIM + d] = h;
        El[k * DDIM + d] = f2bf(v - bf2f(h));
    }
}

// ---------------- MFMA approx scores + top-2 argmin (LDS-shared B, tile pairs) ----------------
// Block = 256 thr = 4 waves; 64 px/block (wave w: px w*16..w*16+15, all 1024 codes).
__global__ void __launch_bounds__(256, 4) gemm_kernel(const float* __restrict__ x,
                                                      const unsigned short* __restrict__ Eh,
                                                      const unsigned short* __restrict__ El,
                                                      const float* __restrict__ esq,
                                                      int* __restrict__ flag,
                                                      int* __restrict__ idx,
                                                      float* __restrict__ out) {
    __shared__ float x_lds[DDIM][64];             // 16KB
    __shared__ float esq_lds[KCODES];             // 4KB
    __shared__ unsigned char btile[2][2][4096];   // 16KB: dbuf pair of B tiles (Eh 2KB | El 2KB), swizzled

    const int tid = threadIdx.x;
    const int w = __builtin_amdgcn_readfirstlane(tid >> 6);
    const int l = tid & 63;
    const int g = l >> 4;              // 0..3
    const int col = l & 15;
    const int pxbase = blockIdx.x * 64;
    const int b = pxbase >> 10;
    const int p0 = pxbase & 1023;

    // stage x tile + esq
    {
        const float* xg = x + (size_t)b * 65536 + p0;
        for (int t = tid; t < DDIM * 64; t += 256)
            x_lds[t >> 6][t & 63] = xg[(size_t)(t >> 6) * 1024 + (t & 63)];
        for (int t = tid; t < KCODES; t += 256)
            esq_lds[t] = esq[t];
    }
    __syncthreads();

    // A fragments: row = col (px_local = w*16+col), k(d)-slot = g*8 + j (+32 per d-half)
    bf16x8 Ah0, Ah1, Al0, Al1;
    {
        const int pxl = w * 16 + col;
#pragma unroll
        for (int j = 0; j < 8; ++j) {
            float v0 = x_lds[g * 8 + j][pxl];
            unsigned short h0 = f2bf(v0);
            Ah0[j] = (short)h0;
            Al0[j] = (short)f2bf(v0 - bf2f(h0));
            float v1 = x_lds[32 + g * 8 + j][pxl];
            unsigned short h1 = f2bf(v1);
            Ah1[j] = (short)h1;
            Al1[j] = (short)f2bf(v1 - bf2f(h1));
        }
    }

    // B staging: thread covers 16B of each 4KB tile. tid<128 -> Eh half, else El.
    // swizzle: dchunk ^= (code&7)<<4 (bijective within each 128B code-row).
    const unsigned short* src_base = (tid < 128) ? Eh : El;
    const int u = tid & 127;
    const int code_w = u >> 3;
    const int dst_off = ((tid >> 7) << 11) + (code_w << 7)
                      + (((u & 7) << 4) ^ ((code_w & 7) << 4));
    float4 stgA, stgB;
    auto LDP = [&](int i) {   // load tiles 2i, 2i+1
        stgA = *(const float4*)((const char*)src_base + (size_t)(2 * i) * 2048 + (size_t)u * 16);
        stgB = *(const float4*)((const char*)src_base + (size_t)(2 * i + 1) * 2048 + (size_t)u * 16);
    };
    auto STP = [&](int i) {   // store tiles 2i, 2i+1 into buf i&1
        *(float4*)&btile[i & 1][0][dst_off] = stgA;
        *(float4*)&btile[i & 1][1][dst_off] = stgB;
    };

    // B read offsets (lane g,col): code-row col*128, d-chunk (g*16 / 64+g*16) ^ (col&7)<<4
    const int cx = (col & 7) << 4;
    const int rb = col << 7;
    const int oh0 = rb + ((g << 4) ^ cx);
    const int oh1 = rb + (((g << 4) + 64) ^ cx);

    float m1_0 = 3.4e38f, m1_1 = 3.4e38f, m1_2 = 3.4e38f, m1_3 = 3.4e38f;
    float m2_0 = 3.4e38f, m2_1 = 3.4e38f, m2_2 = 3.4e38f, m2_3 = 3.4e38f;
    int i1_0 = 0, i1_1 = 0, i1_2 = 0, i1_3 = 0;

#define COMPUTE_TILE(T, BP)                                            \
    {                                                                  \
        const unsigned char* bp_ = (BP);                               \
        const bf16x8 Bh0 = *(const bf16x8*)(bp_ + oh0);                \
        const bf16x8 Bh1 = *(const bf16x8*)(bp_ + oh1);                \
        const bf16x8 Bl0 = *(const bf16x8*)(bp_ + 2048 + oh0);         \
        const bf16x8 Bl1 = *(const bf16x8*)(bp_ + 2048 + oh1);         \
        f32x4 a0 = {0.f, 0.f, 0.f, 0.f};                               \
        f32x4 a1 = {0.f, 0.f, 0.f, 0.f};                               \
        f32x4 a2 = {0.f, 0.f, 0.f, 0.f};                               \
        a0 = __builtin_amdgcn_mfma_f32_16x16x32_bf16(Ah0, Bh0, a0, 0, 0, 0); \
        a1 = __builtin_amdgcn_mfma_f32_16x16x32_bf16(Ah0, Bl0, a1, 0, 0, 0); \
        a2 = __builtin_amdgcn_mfma_f32_16x16x32_bf16(Al0, Bh0, a2, 0, 0, 0); \
        a0 = __builtin_amdgcn_mfma_f32_16x16x32_bf16(Ah1, Bh1, a0, 0, 0, 0); \
        a1 = __builtin_amdgcn_mfma_f32_16x16x32_bf16(Ah1, Bl1, a1, 0, 0, 0); \
        a2 = __builtin_amdgcn_mfma_f32_16x16x32_bf16(Al1, Bh1, a2, 0, 0, 0); \
        const int kc_ = (T) * 16 + col;                                \
        const float qe_ = esq_lds[(T) * 16 + col];                     \
        {                                                              \
            float d_ = (a0[0] + a1[0]) + a2[0];                        \
            float s_ = __builtin_fmaf(-2.0f, d_, qe_);                 \
            float t_ = fmaxf(s_, m1_0);                                \
            m2_0 = fminf(m2_0, t_);                                    \
            if (s_ < m1_0) i1_0 = kc_;                                 \
            m1_0 = fminf(m1_0, s_);                                    \
        }                                                              \
        {                                                              \
            float d_ = (a0[1] + a1[1]) + a2[1];                        \
            float s_ = __builtin_fmaf(-2.0f, d_, qe_);                 \
            float t_ = fmaxf(s_, m1_1);                                \
            m2_1 = fminf(m2_1, t_);                                    \
            if (s_ < m1_1) i1_1 = kc_;                                 \
            m1_1 = fminf(m1_1, s_);                                    \
        }                                                              \
        {                                                              \
            float d_ = (a0[2] + a1[2]) + a2[2];                        \
            float s_ = __builtin_fmaf(-2.0f, d_, qe_);                 \
            float t_ = fmaxf(s_, m1_2);                                \
            m2_2 = fminf(m2_2, t_);                                    \
            if (s_ < m1_2) i1_2 = kc_;                                 \
            m1_2 = fminf(m1_2, s_);                                    \
        }                                                              \
        {                                                              \
            float d_ = (a0[3] + a1[3]) + a2[3];                        \
            float s_ = __builtin_fmaf(-2.0f, d_, qe_);                 \
            float t_ = fmaxf(s_, m1_3);                                \
            m2_3 = fminf(m2_3, t_);                                    \
            if (s_ < m1_3) i1_3 = kc_;                                 \
            m1_3 = fminf(m1_3, s_);                                    \
        }                                                              \
    }

    LDP(0); STP(0);    // pair 0 staged (vmcnt auto before ds_write)
    LDP(1);            // pair 1 in flight
    __syncthreads();

#pragma unroll 1
    for (int i = 0; i < NPAIR; ++i) {
        if (i + 1 < NPAIR) STP(i + 1);    // write pair i+1 (loaded last iter) -> buf (i+1)&1
        if (i + 2 < NPAIR) LDP(i + 2);    // issue loads for pair i+2
        COMPUTE_TILE(2 * i,     &btile[i & 1][0][0])
        COMPUTE_TILE(2 * i + 1, &btile[i & 1][1][0])
        __syncthreads();
    }
#undef COMPUTE_TILE

    // cross-lane merge over the 16 lanes of group g (same px rows)
#define MERGE(M1, M2, I1, R)                                                   \
    {                                                                          \
        float a1_ = M1, a2_ = M2; int j1 = I1;                                 \
        _Pragma("unroll")                                                      \
        for (int off = 1; off < 16; off <<= 1) {                               \
            float b1 = __shfl_xor(a1_, off);                                   \
            int jb = __shfl_xor(j1, off);                                      \
            float b2 = __shfl_xor(a2_, off);                                   \
            float hi = fmaxf(a1_, b1);                                         \
            a2_ = fminf(fminf(a2_, b2), hi);                                   \
            if (b1 < a1_) j1 = jb;                                             \
            a1_ = fminf(a1_, b1);                                              \
        }                                                                      \
        if (col == 0) {                                                        \
            int px = pxbase + w * 16 + g * 4 + (R);                            \
            flag[px] = (a2_ <= a1_ + MARGIN) ? 1 : 0;                          \
            idx[px] = j1;                                                      \
            out[IDX_OFF + px] = (float)j1;                                     \
        }                                                                      \
    }
    MERGE(m1_0, m2_0, i1_0, 0)
    MERGE(m1_1, m2_1, i1_1, 1)
    MERGE(m1_2, m2_2, i1_2, 2)
    MERGE(m1_3, m2_3, i1_3, 3)
#undef MERGE
}

// ---------------- compact flagged pixels into a list ----------------
__global__ void __launch_bounds__(256) compact_kernel(const int* __restrict__ flag,
                                                      int* __restrict__ count,
                                                      int* __restrict__ list) {
    const int p = blockIdx.x * 256 + threadIdx.x;
    const int lane = threadIdx.x & 63;
    const bool f = flag[p] != 0;
    unsigned long long m = __ballot(f);
    int base = 0;
    if (lane == 0 && m) base = atomicAdd(count, __popcll(m));
    base = __shfl(base, 0);
    if (f) {
        unsigned long long below = m & ((1ULL << lane) - 1ULL);
        list[base + __popcll(below)] = p;
    }
}

// ---------------- cleanup: exact reference argmin over the compacted list ----------------
// 2048 blocks x 256 thr grid-stride the list; one block-cooperative solve per
// pixel: thread t owns codes [4t,4t+4) ascending, exact d-ascending fp32
// chains; lexicographic (s,k) reduce == first-occurrence argmin.
__global__ void __launch_bounds__(256) cleanup_kernel(const float* __restrict__ x,
                                                      const float* __restrict__ e,
                                                      const float* __restrict__ esq,
                                                      const int* __restrict__ count,
                                                      const int* __restrict__ list,
                                                      int* __restrict__ idx,
                                                      float* __restrict__ out) {
    __shared__ float xs[DDIM];
    __shared__ float rbest[4];
    __shared__ int   ridx[4];

    const int tid = threadIdx.x;
    const int cnt = *count;

    for (int j = blockIdx.x; j < cnt; j += gridDim.x) {
        const int p = list[j];
        if (tid < 64)
            xs[tid] = x[(size_t)(p >> 10) * 65536 + (size_t)tid * 1024 + (p & 1023)];
        __syncthreads();

        // xsq: EXACT numpy pairwise-8 (broadcast LDS reads)
        float xsq;
        {
#pragma clang fp contract(off)
            float r[8];
#pragma unroll
            for (int jj = 0; jj < 8; ++jj) { float v = xs[jj]; r[jj] = v * v; }
#pragma unroll
            for (int ii = 1; ii < 8; ++ii) {
#pragma unroll
                for (int jj = 0; jj < 8; ++jj) { float v = xs[ii * 8 + jj]; r[jj] += v * v; }
            }
            xsq = ((r[0] + r[1]) + (r[2] + r[3])) + ((r[4] + r[5]) + (r[6] + r[7]));
        }

        // thread t: codes 4t..4t+3, exact reference chain per code
        float best = 3.4e38f;
        int bi = 0;
#pragma unroll
        for (int c = 0; c < 4; ++c) {
            const int k = tid * 4 + c;
            const float* er = e + (size_t)k * DDIM;
            float dt = 0.f;
#pragma unroll
            for (int d = 0; d < DDIM; ++d) dt = __builtin_fmaf(xs[d], er[d], dt);
            const float s = (xsq - 2.0f * dt) + esq[k];
            if (s < best) { best = s; bi = k; }
        }
        // wave reduce lexicographic (s,k): lowest s, ties -> lowest k
#pragma unroll
        for (int off = 1; off < 64; off <<= 1) {
            float b2 = __shfl_xor(best, off);
            int k2 = __shfl_xor(bi, off);
            if (b2 < best || (b2 == best && k2 < bi)) { best = b2; bi = k2; }
        }
        if ((tid & 63) == 0) { rbest[tid >> 6] = best; ridx[tid >> 6] = bi; }
        __syncthreads();
        if (tid == 0) {
            float bb = rbest[0]; int bj = ridx[0];
#pragma unroll
            for (int c2 = 1; c2 < 4; ++c2) {
                if (rbest[c2] < bb || (rbest[c2] == bb && ridx[c2] < bj)) {
                    bb = rbest[c2]; bj = ridx[c2];
                }
            }
            idx[p] = bj;
            out[IDX_OFF + p] = (float)bj;
        }
        __syncthreads();   // xs/rbest safe to overwrite next iteration
    }
}

// ---------------- gather + transpose + per-block loss partials ----------------
__global__ void __launch_bounds__(256) gather_kernel(const float* __restrict__ x,
                                                     const float* __restrict__ e,
                                                     const int* __restrict__ idx,
                                                     float* __restrict__ out,
                                                     float* __restrict__ partial) {
    const int bd = blockIdx.x;          // = b*64 + d
    const int b = bd >> 6;
    const int d = bd & 63;
    const size_t base = (size_t)bd * 1024;
    const int* idxb = idx + b * 1024;

    float acc = 0.f;
#pragma unroll
    for (int j = 0; j < 4; ++j) {
        int p = threadIdx.x + j * 256;
        int k = idxb[p];
        float ev = e[k * 64 + d];
        float xv = x[base + p];
        out[1 + base + p] = ev;
        float df = ev - xv;
        acc = __builtin_fmaf(df, df, acc);
    }
    __shared__ float sm[256];
    sm[threadIdx.x] = acc;
    __syncthreads();
    for (int s = 128; s > 0; s >>= 1) {
        if (threadIdx.x < s) sm[threadIdx.x] += sm[threadIdx.x + s];
        __syncthreads();
    }
    if (threadIdx.x == 0) partial[bd] = sm[0];
}

__global__ void __launch_bounds__(256) loss_kernel(const float* __restrict__ partial,
                                                   float* __restrict__ out) {
    float acc = 0.f;
    for (int i = threadIdx.x; i < 4096; i += 256) acc += partial[i];
    __shared__ float sm[256];
    sm[threadIdx.x] = acc;
    __syncthreads();
    for (int s = 128; s > 0; s >>= 1) {
        if (threadIdx.x < s) sm[threadIdx.x] += sm[threadIdx.x + s];
        __syncthreads();
    }
    if (threadIdx.x == 0) out[0] = sm[0] * (1.25f / 4194304.f);
}

extern "C" void kernel_launch(void* const* d_in, const int* in_sizes, int n_in,
                              void* d_out, int out_size, void* d_ws, size_t ws_size,
                              hipStream_t stream) {
    const float* x = (const float*)d_in[0];   // [64,64,32,32]
    const float* e = (const float*)d_in[1];   // [1024,64]
    float* out = (float*)d_out;

    // ws: esq 4KB | Eh 128KB | El 128KB | flag 256KB | idx 256KB | partial 16KB | count 4KB | list 256KB
    char* wsb = (char*)d_ws;
    float*          esq     = (float*)wsb;
    unsigned short* Eh      = (unsigned short*)(wsb + 4096);
    unsigned short* El      = (unsigned short*)(wsb + 4096 + 131072);
    int*            flag    = (int*)(wsb + 4096 + 2 * 131072);
    int*            idx     = (int*)(wsb + 4096 + 2 * 131072 + NPIX * 4);
    float*          partial = (float*)(wsb + 4096 + 2 * 131072 + 2 * NPIX * 4);
    int*            count   = (int*)(wsb + 4096 + 2 * 131072 + 2 * NPIX * 4 + 16384);
    int*            list    = (int*)(wsb + 4096 + 2 * 131072 + 2 * NPIX * 4 + 16384 + 4096);

    esplit_kernel<<<4, 256, 0, stream>>>(e, esq, Eh, El, count);
    gemm_kernel<<<NPIX / 64, 256, 0, stream>>>(x, Eh, El, esq, flag, idx, out);
    compact_kernel<<<NPIX / 256, 256, 0, stream>>>(flag, count, list);
    cleanup_kernel<<<2048, 256, 0, stream>>>(x, e, esq, count, list, idx, out);
    gather_kernel<<<4096, 256, 0, stream>>>(x, e, idx, out, partial);
    loss_kernel<<<1, 256, 0, stream>>>(partial, out);
}

// Round 17
// 119.642 us; speedup vs baseline: 1.3523x; 1.3523x over previous
//
#include <hip/hip_runtime.h>

// VQ-VAE VectorQuantizer forward, fp32, MI355X.
// B=64, C=D=64, H=W=32 -> N=65536 pixels, K=1024 codes.
// Outputs (flat concat): [0] loss, [1..4194305) quantized BCHW, [4194305..) indices (as float)
//
// R17: cleanup v3. R16's 85us was the address-divergent e-gather (each lane
// its own 256B row -> 64 lines per wave-load -> ~36M L2 lane-transactions).
// Now: block handles 8 flagged pixels; e staged per 256-code tile (64KB) with
// COALESCED float4 reads into transpose layout tile[d][257] (+1 pad -> both
// staging writes and chain reads conflict-free); thread t chains code
// T*256+t from LDS. Exact chain arithmetic BIT-IDENTICAL to R0-R16 (passed,
// absmax 3.8e-6): pairwise-8 x_sq (contract off), d-ascending fp32 FMA,
// (xsq-2d)+esq, per-thread ascending codes + lexicographic (s,k) reduce ==
// first-occurrence argmin. gemm/compact/gather unchanged from R16.

#define KCODES 1024
#define DDIM   64
#define NPIX   65536
#define QELEMS 4194304
#define IDX_OFF (1 + QELEMS)
#define MARGIN 8e-5f
#define NPAIR  32          // 64 tiles / 2 per iteration
#define NB     8           // pixels per cleanup chunk

typedef __attribute__((ext_vector_type(8))) short bf16x8;
typedef __attribute__((ext_vector_type(4))) float f32x4;

static __device__ __forceinline__ unsigned short f2bf(float f) {
    unsigned int u = __float_as_uint(f);
    unsigned int r = (u + 0x7FFFu + ((u >> 16) & 1u)) >> 16;   // RNE
    return (unsigned short)r;
}
static __device__ __forceinline__ float bf2f(unsigned short h) {
    return __uint_as_float(((unsigned int)h) << 16);
}

// ---------------- e prep: esq (EXACT numpy pairwise-8) + bf16 split + counter zero ----------------
__global__ void __launch_bounds__(256) esplit_kernel(const float* __restrict__ e,
                                                     float* __restrict__ esq,
                                                     unsigned short* __restrict__ Eh,
                                                     unsigned short* __restrict__ El,
                                                     int* __restrict__ count) {
    if (blockIdx.x == 0 && threadIdx.x == 0) *count = 0;
    int k = blockIdx.x * 256 + threadIdx.x;
    if (k >= KCODES) return;
    const float* row = e + k * DDIM;
    {
#pragma clang fp contract(off)
        float r[8];
#pragma unroll
        for (int j = 0; j < 8; ++j) r[j] = row[j] * row[j];
#pragma unroll
        for (int i = 1; i < 8; ++i) {
#pragma unroll
            for (int j = 0; j < 8; ++j) { float v = row[i * 8 + j]; r[j] += v * v; }
        }
        esq[k] = ((r[0] + r[1]) + (r[2] + r[3])) + ((r[4] + r[5]) + (r[6] + r[7]));
    }
#pragma unroll
    for (int d = 0; d < DDIM; ++d) {
        float v = row[d];
        unsigned short h = f2bf(v);
        Eh[k * DDIM + d] = h;
        El[k * DDIM + d] = f2bf(v - bf2f(h));
    }
}

// ---------------- MFMA approx scores + top-2 argmin (LDS-shared B, tile pairs) ----------------
// Block = 256 thr = 4 waves; 64 px/block (wave w: px w*16..w*16+15, all 1024 codes).
__global__ void __launch_bounds__(256, 4) gemm_kernel(const float* __restrict__ x,
                                                      const unsigned short* __restrict__ Eh,
                                                      const unsigned short* __restrict__ El,
                                                      const float* __restrict__ esq,
                                                      int* __restrict__ flag,
                                                      int* __restrict__ idx,
                                                      float* __restrict__ out) {
    __shared__ float x_lds[DDIM][64];             // 16KB
    __shared__ float esq_lds[KCODES];             // 4KB
    __shared__ unsigned char btile[2][2][4096];   // 16KB: dbuf pair of B tiles (Eh 2KB | El 2KB), swizzled

    const int tid = threadIdx.x;
    const int w = __builtin_amdgcn_readfirstlane(tid >> 6);
    const int l = tid & 63;
    const int g = l >> 4;              // 0..3
    const int col = l & 15;
    const int pxbase = blockIdx.x * 64;
    const int b = pxbase >> 10;
    const int p0 = pxbase & 1023;

    // stage x tile + esq
    {
        const float* xg = x + (size_t)b * 65536 + p0;
        for (int t = tid; t < DDIM * 64; t += 256)
            x_lds[t >> 6][t & 63] = xg[(size_t)(t >> 6) * 1024 + (t & 63)];
        for (int t = tid; t < KCODES; t += 256)
            esq_lds[t] = esq[t];
    }
    __syncthreads();

    // A fragments: row = col (px_local = w*16+col), k(d)-slot = g*8 + j (+32 per d-half)
    bf16x8 Ah0, Ah1, Al0, Al1;
    {
        const int pxl = w * 16 + col;
#pragma unroll
        for (int j = 0; j < 8; ++j) {
            float v0 = x_lds[g * 8 + j][pxl];
            unsigned short h0 = f2bf(v0);
            Ah0[j] = (short)h0;
            Al0[j] = (short)f2bf(v0 - bf2f(h0));
            float v1 = x_lds[32 + g * 8 + j][pxl];
            unsigned short h1 = f2bf(v1);
            Ah1[j] = (short)h1;
            Al1[j] = (short)f2bf(v1 - bf2f(h1));
        }
    }

    // B staging: thread covers 16B of each 4KB tile. tid<128 -> Eh half, else El.
    // swizzle: dchunk ^= (code&7)<<4 (bijective within each 128B code-row).
    const unsigned short* src_base = (tid < 128) ? Eh : El;
    const int u = tid & 127;
    const int code_w = u >> 3;
    const int dst_off = ((tid >> 7) << 11) + (code_w << 7)
                      + (((u & 7) << 4) ^ ((code_w & 7) << 4));
    float4 stgA, stgB;
    auto LDP = [&](int i) {   // load tiles 2i, 2i+1
        stgA = *(const float4*)((const char*)src_base + (size_t)(2 * i) * 2048 + (size_t)u * 16);
        stgB = *(const float4*)((const char*)src_base + (size_t)(2 * i + 1) * 2048 + (size_t)u * 16);
    };
    auto STP = [&](int i) {   // store tiles 2i, 2i+1 into buf i&1
        *(float4*)&btile[i & 1][0][dst_off] = stgA;
        *(float4*)&btile[i & 1][1][dst_off] = stgB;
    };

    // B read offsets (lane g,col): code-row col*128, d-chunk (g*16 / 64+g*16) ^ (col&7)<<4
    const int cx = (col & 7) << 4;
    const int rb = col << 7;
    const int oh0 = rb + ((g << 4) ^ cx);
    const int oh1 = rb + (((g << 4) + 64) ^ cx);

    float m1_0 = 3.4e38f, m1_1 = 3.4e38f, m1_2 = 3.4e38f, m1_3 = 3.4e38f;
    float m2_0 = 3.4e38f, m2_1 = 3.4e38f, m2_2 = 3.4e38f, m2_3 = 3.4e38f;
    int i1_0 = 0, i1_1 = 0, i1_2 = 0, i1_3 = 0;

#define COMPUTE_TILE(T, BP)                                            \
    {                                                                  \
        const unsigned char* bp_ = (BP);                               \
        const bf16x8 Bh0 = *(const bf16x8*)(bp_ + oh0);                \
        const bf16x8 Bh1 = *(const bf16x8*)(bp_ + oh1);                \
        const bf16x8 Bl0 = *(const bf16x8*)(bp_ + 2048 + oh0);         \
        const bf16x8 Bl1 = *(const bf16x8*)(bp_ + 2048 + oh1);         \
        f32x4 a0 = {0.f, 0.f, 0.f, 0.f};                               \
        f32x4 a1 = {0.f, 0.f, 0.f, 0.f};                               \
        f32x4 a2 = {0.f, 0.f, 0.f, 0.f};                               \
        a0 = __builtin_amdgcn_mfma_f32_16x16x32_bf16(Ah0, Bh0, a0, 0, 0, 0); \
        a1 = __builtin_amdgcn_mfma_f32_16x16x32_bf16(Ah0, Bl0, a1, 0, 0, 0); \
        a2 = __builtin_amdgcn_mfma_f32_16x16x32_bf16(Al0, Bh0, a2, 0, 0, 0); \
        a0 = __builtin_amdgcn_mfma_f32_16x16x32_bf16(Ah1, Bh1, a0, 0, 0, 0); \
        a1 = __builtin_amdgcn_mfma_f32_16x16x32_bf16(Ah1, Bl1, a1, 0, 0, 0); \
        a2 = __builtin_amdgcn_mfma_f32_16x16x32_bf16(Al1, Bh1, a2, 0, 0, 0); \
        const int kc_ = (T) * 16 + col;                                \
        const float qe_ = esq_lds[(T) * 16 + col];                     \
        {                                                              \
            float d_ = (a0[0] + a1[0]) + a2[0];                        \
            float s_ = __builtin_fmaf(-2.0f, d_, qe_);                 \
            float t_ = fmaxf(s_, m1_0);                                \
            m2_0 = fminf(m2_0, t_);                                    \
            if (s_ < m1_0) i1_0 = kc_;                                 \
            m1_0 = fminf(m1_0, s_);                                    \
        }                                                              \
        {                                                              \
            float d_ = (a0[1] + a1[1]) + a2[1];                        \
            float s_ = __builtin_fmaf(-2.0f, d_, qe_);                 \
            float t_ = fmaxf(s_, m1_1);                                \
            m2_1 = fminf(m2_1, t_);                                    \
            if (s_ < m1_1) i1_1 = kc_;                                 \
            m1_1 = fminf(m1_1, s_);                                    \
        }                                                              \
        {                                                              \
            float d_ = (a0[2] + a1[2]) + a2[2];                        \
            float s_ = __builtin_fmaf(-2.0f, d_, qe_);                 \
            float t_ = fmaxf(s_, m1_2);                                \
            m2_2 = fminf(m2_2, t_);                                    \
            if (s_ < m1_2) i1_2 = kc_;                                 \
            m1_2 = fminf(m1_2, s_);                                    \
        }                                                              \
        {                                                              \
            float d_ = (a0[3] + a1[3]) + a2[3];                        \
            float s_ = __builtin_fmaf(-2.0f, d_, qe_);                 \
            float t_ = fmaxf(s_, m1_3);                                \
            m2_3 = fminf(m2_3, t_);                                    \
            if (s_ < m1_3) i1_3 = kc_;                                 \
            m1_3 = fminf(m1_3, s_);                                    \
        }                                                              \
    }

    LDP(0); STP(0);    // pair 0 staged (vmcnt auto before ds_write)
    LDP(1);            // pair 1 in flight
    __syncthreads();

#pragma unroll 1
    for (int i = 0; i < NPAIR; ++i) {
        if (i + 1 < NPAIR) STP(i + 1);    // write pair i+1 (loaded last iter) -> buf (i+1)&1
        if (i + 2 < NPAIR) LDP(i + 2);    // issue loads for pair i+2
        COMPUTE_TILE(2 * i,     &btile[i & 1][0][0])
        COMPUTE_TILE(2 * i + 1, &btile[i & 1][1][0])
        __syncthreads();
    }
#undef COMPUTE_TILE

    // cross-lane merge over the 16 lanes of group g (same px rows)
#define MERGE(M1, M2, I1, R)                                                   \
    {                                                                          \
        float a1_ = M1, a2_ = M2; int j1 = I1;                                 \
        _Pragma("unroll")                                                      \
        for (int off = 1; off < 16; off <<= 1) {                               \
            float b1 = __shfl_xor(a1_, off);                                   \
            int jb = __shfl_xor(j1, off);                                      \
            float b2 = __shfl_xor(a2_, off);                                   \
            float hi = fmaxf(a1_, b1);                                         \
            a2_ = fminf(fminf(a2_, b2), hi);                                   \
            if (b1 < a1_) j1 = jb;                                             \
            a1_ = fminf(a1_, b1);                                              \
        }                                                                      \
        if (col == 0) {                                                        \
            int px = pxbase + w * 16 + g * 4 + (R);                            \
            flag[px] = (a2_ <= a1_ + MARGIN) ? 1 : 0;                          \
            idx[px] = j1;                                                      \
            out[IDX_OFF + px] = (float)j1;                                     \
        }                                                                      \
    }
    MERGE(m1_0, m2_0, i1_0, 0)
    MERGE(m1_1, m2_1, i1_1, 1)
    MERGE(m1_2, m2_2, i1_2, 2)
    MERGE(m1_3, m2_3, i1_3, 3)
#undef MERGE
}

// ---------------- compact flagged pixels into a list ----------------
__global__ void __launch_bounds__(256) compact_kernel(const int* __restrict__ flag,
                                                      int* __restrict__ count,
                                                      int* __restrict__ list) {
    const int p = blockIdx.x * 256 + threadIdx.x;
    const int lane = threadIdx.x & 63;
    const bool f = flag[p] != 0;
    unsigned long long m = __ballot(f);
    int base = 0;
    if (lane == 0 && m) base = atomicAdd(count, __popcll(m));
    base = __shfl(base, 0);
    if (f) {
        unsigned long long below = m & ((1ULL << lane) - 1ULL);
        list[base + __popcll(below)] = p;
    }
}

// ---------------- cleanup v3: exact argmin, e tiled through LDS (coalesced) ----------------
// Block: NB=8 pixels per chunk. 4 tiles of 256 codes: staged via coalesced
// float4 global reads into transpose layout tile[d][257] (+1 pad -> staging
// writes AND chain reads bank-conflict-free). Thread t chains code T*256+t
// (per-thread ascending); lexicographic (s,k) reduce == first-occurrence.
__global__ void __launch_bounds__(256, 4) cleanup_kernel(const float* __restrict__ x,
                                                         const float* __restrict__ e,
                                                         const float* __restrict__ esq,
                                                         const int* __restrict__ count,
                                                         const int* __restrict__ list,
                                                         int* __restrict__ idx,
                                                         float* __restrict__ out) {
    __shared__ float tile[DDIM][257];   // 65.8KB transpose tile
    __shared__ float xs[NB][68];        // padded: xsq-phase banks (4j+d)%32 spread
    __shared__ float xsqs[NB];
    __shared__ float rbest[4];
    __shared__ int   ridx[4];
    __shared__ int   plist[NB];

    const int tid = threadIdx.x;
    const int cnt = *count;
    const int nchunk = (cnt + NB - 1) / NB;

    for (int chunk = blockIdx.x; chunk < nchunk; chunk += gridDim.x) {
        const int base = chunk * NB;
        const int np = min(NB, cnt - base);      // block-uniform

        if (tid < np) plist[tid] = list[base + tid];
        __syncthreads();
        // stage x rows for the chunk's pixels
        for (int q = tid; q < np * 64; q += 256) {
            const int pp = q >> 6, d = q & 63;
            const int p = plist[pp];
            xs[pp][d] = x[(size_t)(p >> 10) * 65536 + (size_t)d * 1024 + (p & 1023)];
        }
        __syncthreads();
        // xsq: EXACT numpy pairwise-8 (contract off), one pixel per low thread
        if (tid < np) {
#pragma clang fp contract(off)
            float r[8];
#pragma unroll
            for (int j = 0; j < 8; ++j) { float v = xs[tid][j]; r[j] = v * v; }
#pragma unroll
            for (int ii = 1; ii < 8; ++ii) {
#pragma unroll
                for (int j = 0; j < 8; ++j) { float v = xs[tid][ii * 8 + j]; r[j] += v * v; }
            }
            xsqs[tid] = ((r[0] + r[1]) + (r[2] + r[3])) + ((r[4] + r[5]) + (r[6] + r[7]));
        }

        float best[NB];
        int bidx[NB];
#pragma unroll
        for (int pp = 0; pp < NB; ++pp) { best[pp] = 3.4e38f; bidx[pp] = 0; }

#pragma unroll 1
        for (int T = 0; T < 4; ++T) {
            __syncthreads();   // xsqs ready (T=0) / prior tile reads done (T>0)
            // stage tile T: thread t iter i -> code 16i+(t>>4), d0=(4t)&63 (coalesced float4)
#pragma unroll
            for (int i = 0; i < 16; ++i) {
                const float4 v = *(const float4*)(e + (size_t)T * 16384 + (size_t)i * 1024 + tid * 4);
                const int c = 16 * i + (tid >> 4);
                const int d0 = (4 * tid) & 63;
                tile[d0 + 0][c] = v.x;
                tile[d0 + 1][c] = v.y;
                tile[d0 + 2][c] = v.z;
                tile[d0 + 3][c] = v.w;
            }
            __syncthreads();
            const float qe = esq[T * 256 + tid];   // coalesced
            const int kk = T * 256 + tid;
#pragma unroll
            for (int pp = 0; pp < NB; ++pp) {
                if (pp < np) {
                    // exact d-ascending fp32 FMA chain (values = exact copies)
                    float dt = 0.f;
#pragma unroll
                    for (int d = 0; d < DDIM; ++d)
                        dt = __builtin_fmaf(xs[pp][d], tile[d][tid], dt);
                    const float s = (xsqs[pp] - 2.0f * dt) + qe;
                    if (s < best[pp]) { best[pp] = s; bidx[pp] = kk; }
                }
            }
        }

        // per-pixel reduce: lexicographic (s,k) over 256 threads
#pragma unroll
        for (int pp = 0; pp < NB; ++pp) {
            if (pp < np) {                       // block-uniform -> barriers safe
                float bb = best[pp];
                int bj = bidx[pp];
#pragma unroll
                for (int off = 1; off < 64; off <<= 1) {
                    float b2 = __shfl_xor(bb, off);
                    int k2 = __shfl_xor(bj, off);
                    if (b2 < bb || (b2 == bb && k2 < bj)) { bb = b2; bj = k2; }
                }
                if ((tid & 63) == 0) { rbest[tid >> 6] = bb; ridx[tid >> 6] = bj; }
                __syncthreads();
                if (tid == 0) {
                    float b0 = rbest[0]; int j0 = ridx[0];
#pragma unroll
                    for (int c2 = 1; c2 < 4; ++c2)
                        if (rbest[c2] < b0 || (rbest[c2] == b0 && ridx[c2] < j0)) {
                            b0 = rbest[c2]; j0 = ridx[c2];
                        }
                    const int p = plist[pp];
                    idx[p] = j0;
                    out[IDX_OFF + p] = (float)j0;
                }
                __syncthreads();
            }
        }
        __syncthreads();   // plist/xs safe to overwrite next chunk
    }
}

// ---------------- gather + transpose + per-block loss partials ----------------
__global__ void __launch_bounds__(256) gather_kernel(const float* __restrict__ x,
                                                     const float* __restrict__ e,
                                                     const int* __restrict__ idx,
                                                     float* __restrict__ out,
                                                     float* __restrict__ partial) {
    const int bd = blockIdx.x;          // = b*64 + d
    const int b = bd >> 6;
    const int d = bd & 63;
    const size_t base = (size_t)bd * 1024;
    const int* idxb = idx + b * 1024;

    float acc = 0.f;
#pragma unroll
    for (int j = 0; j < 4; ++j) {
        int p = threadIdx.x + j * 256;
        int k = idxb[p];
        float ev = e[k * 64 + d];
        float xv = x[base + p];
        out[1 + base + p] = ev;
        float df = ev - xv;
        acc = __builtin_fmaf(df, df, acc);
    }
    __shared__ float sm[256];
    sm[threadIdx.x] = acc;
    __syncthreads();
    for (int s = 128; s > 0; s >>= 1) {
        if (threadIdx.x < s) sm[threadIdx.x] += sm[threadIdx.x + s];
        __syncthreads();
    }
    if (threadIdx.x == 0) partial[bd] = sm[0];
}

__global__ void __launch_bounds__(256) loss_kernel(const float* __restrict__ partial,
                                                   float* __restrict__ out) {
    float acc = 0.f;
    for (int i = threadIdx.x; i < 4096; i += 256) acc += partial[i];
    __shared__ float sm[256];
    sm[threadIdx.x] = acc;
    __syncthreads();
    for (int s = 128; s > 0; s >>= 1) {
        if (threadIdx.x < s) sm[threadIdx.x] += sm[threadIdx.x + s];
        __syncthreads();
    }
    if (threadIdx.x == 0) out[0] = sm[0] * (1.25f / 4194304.f);
}

extern "C" void kernel_launch(void* const* d_in, const int* in_sizes, int n_in,
                              void* d_out, int out_size, void* d_ws, size_t ws_size,
                              hipStream_t stream) {
    const float* x = (const float*)d_in[0];   // [64,64,32,32]
    const float* e = (const float*)d_in[1];   // [1024,64]
    float* out = (float*)d_out;

    // ws: esq 4KB | Eh 128KB | El 128KB | flag 256KB | idx 256KB | partial 16KB | count 4KB | list 256KB
    char* wsb = (char*)d_ws;
    float*          esq     = (float*)wsb;
    unsigned short* Eh      = (unsigned short*)(wsb + 4096);
    unsigned short* El      = (unsigned short*)(wsb + 4096 + 131072);
    int*            flag    = (int*)(wsb + 4096 + 2 * 131072);
    int*            idx     = (int*)(wsb + 4096 + 2 * 131072 + NPIX * 4);
    float*          partial = (float*)(wsb + 4096 + 2 * 131072 + 2 * NPIX * 4);
    int*            count   = (int*)(wsb + 4096 + 2 * 131072 + 2 * NPIX * 4 + 16384);
    int*            list    = (int*)(wsb + 4096 + 2 * 131072 + 2 * NPIX * 4 + 16384 + 4096);

    esplit_kernel<<<4, 256, 0, stream>>>(e, esq, Eh, El, count);
    gemm_kernel<<<NPIX / 64, 256, 0, stream>>>(x, Eh, El, esq, flag, idx, out);
    compact_kernel<<<NPIX / 256, 256, 0, stream>>>(flag, count, list);
    cleanup_kernel<<<512, 256, 0, stream>>>(x, e, esq, count, list, idx, out);
    gather_kernel<<<4096, 256, 0, stream>>>(x, e, idx, out, partial);
    loss_kernel<<<1, 256, 0, stream>>>(partial, out);
}

// Round 18
// 110.035 us; speedup vs baseline: 1.4704x; 1.0873x over previous
//
#include <hip/hip_runtime.h>

// VQ-VAE VectorQuantizer forward, fp32, MI355X.
// B=64, C=D=64, H=W=32 -> N=65536 pixels, K=1024 codes.
// Outputs (flat concat): [0] loss, [1..4194305) quantized BCHW, [4194305..) indices (as float)
//
// R18: gemm densified. R17: MfmaUtil 23% / VALUBusy 41% -> ~50% dead cycles
// (barrier every 2 tiles, short dep chains, 2.5 blocks/CU). Now:
// (a) 128 px/block — two A-frag sets share each B tile: 12 MFMA + 8 score
//     streams per window, half the barriers/B-traffic per MFMA. LDS 52KB,
//     launch_bounds(256,3) cap 170 vs ~130 demand (spill tripwire: WRITE_SIZE).
// (b) esq-fold: Eh/El store bf16-split of (-2e) (exact x2 scaling); acc
//     inits to {qe} -> epilogue = 2 adds + top2 (no fma). Deviation budget
//     ~1.5e-5 << MARGIN/2.
// (c) compact fused into gemm (LDS flags + block-end ballot/atomicAdd).
// MARGIN 8e-5 (R14-17 validated). Exact-path arithmetic BIT-IDENTICAL to
// R0-R17 (passed, absmax 3.8e-6): pairwise-8 x_sq (contract off),
// d-ascending fp32 FMA chain, (xsq-2d)+esq, first-occurrence argmin.

#define KCODES 1024
#define DDIM   64
#define NPIX   65536
#define QELEMS 4194304
#define IDX_OFF (1 + QELEMS)
#define MARGIN 8e-5f
#define NPAIR  32          // 64 tiles / 2 per iteration
#define PXB    128         // pixels per gemm block
#define NB     8           // pixels per cleanup chunk

typedef __attribute__((ext_vector_type(8))) short bf16x8;
typedef __attribute__((ext_vector_type(4))) float f32x4;

static __device__ __forceinline__ unsigned short f2bf(float f) {
    unsigned int u = __float_as_uint(f);
    unsigned int r = (u + 0x7FFFu + ((u >> 16) & 1u)) >> 16;   // RNE
    return (unsigned short)r;
}
static __device__ __forceinline__ float bf2f(unsigned short h) {
    return __uint_as_float(((unsigned int)h) << 16);
}

// ---------------- e prep: esq (EXACT pairwise-8) + bf16 split of (-2e) ----------------
__global__ void __launch_bounds__(256) esplit_kernel(const float* __restrict__ e,
                                                     float* __restrict__ esq,
                                                     unsigned short* __restrict__ Eh,
                                                     unsigned short* __restrict__ El,
                                                     int* __restrict__ count) {
    if (blockIdx.x == 0 && threadIdx.x == 0) *count = 0;
    int k = blockIdx.x * 256 + threadIdx.x;
    if (k >= KCODES) return;
    const float* row = e + k * DDIM;
    {
#pragma clang fp contract(off)
        float r[8];
#pragma unroll
        for (int j = 0; j < 8; ++j) r[j] = row[j] * row[j];
#pragma unroll
        for (int i = 1; i < 8; ++i) {
#pragma unroll
            for (int j = 0; j < 8; ++j) { float v = row[i * 8 + j]; r[j] += v * v; }
        }
        esq[k] = ((r[0] + r[1]) + (r[2] + r[3])) + ((r[4] + r[5]) + (r[6] + r[7]));
    }
#pragma unroll
    for (int d = 0; d < DDIM; ++d) {
        float v = -2.0f * row[d];              // exact
        unsigned short h = f2bf(v);
        Eh[k * DDIM + d] = h;
        El[k * DDIM + d] = f2bf(v - bf2f(h));
    }
}

// ---------------- MFMA approx scores + top-2 argmin + fused compact ----------------
// Block = 256 thr = 4 waves; 128 px/block. Wave w: px rows {w*16..w*16+15} and
// {64+w*16..}, all 1024 codes. B tiles (of -2e) LDS-shared, dbuf pairs, swizzled.
__global__ void __launch_bounds__(256, 3) gemm_kernel(const float* __restrict__ x,
                                                      const unsigned short* __restrict__ Eh,
                                                      const unsigned short* __restrict__ El,
                                                      const float* __restrict__ esq,
                                                      int* __restrict__ count,
                                                      int* __restrict__ list,
                                                      int* __restrict__ idx,
                                                      float* __restrict__ out) {
    __shared__ float x_lds[DDIM][PXB];            // 32KB
    __shared__ float esq_lds[KCODES];             // 4KB
    __shared__ unsigned char btile[2][2][4096];   // 16KB dbuf pair (Eh 2KB | El 2KB), swizzled
    __shared__ int sflag[PXB];

    const int tid = threadIdx.x;
    const int w = __builtin_amdgcn_readfirstlane(tid >> 6);
    const int l = tid & 63;
    const int g = l >> 4;              // 0..3
    const int col = l & 15;
    const int pxbase = blockIdx.x * PXB;
    const int b = pxbase >> 10;
    const int p0 = pxbase & 1023;

    // stage x tile (coalesced 512B rows) + esq
    {
        const float* xg = x + (size_t)b * 65536 + p0;
        for (int t = tid; t < DDIM * PXB; t += 256)
            x_lds[t >> 7][t & 127] = xg[(size_t)(t >> 7) * 1024 + (t & 127)];
        for (int t = tid; t < KCODES; t += 256)
            esq_lds[t] = esq[t];
    }
    __syncthreads();

    // A fragments, two pixel sets: rows w*16+col and 64+w*16+col; k-slot g*8+j (+32)
    bf16x8 A0h0, A0h1, A0l0, A0l1, A1h0, A1h1, A1l0, A1l1;
    {
        const int pxl = w * 16 + col;
#pragma unroll
        for (int j = 0; j < 8; ++j) {
            float v0 = x_lds[g * 8 + j][pxl];
            unsigned short h0 = f2bf(v0);
            A0h0[j] = (short)h0;
            A0l0[j] = (short)f2bf(v0 - bf2f(h0));
            float v1 = x_lds[32 + g * 8 + j][pxl];
            unsigned short h1 = f2bf(v1);
            A0h1[j] = (short)h1;
            A0l1[j] = (short)f2bf(v1 - bf2f(h1));
            float u0 = x_lds[g * 8 + j][pxl + 64];
            unsigned short k0 = f2bf(u0);
            A1h0[j] = (short)k0;
            A1l0[j] = (short)f2bf(u0 - bf2f(k0));
            float u1 = x_lds[32 + g * 8 + j][pxl + 64];
            unsigned short k1 = f2bf(u1);
            A1h1[j] = (short)k1;
            A1l1[j] = (short)f2bf(u1 - bf2f(k1));
        }
    }

    // B staging (same as R17): thread covers 16B per tile; swizzle dchunk ^= (code&7)<<4
    const unsigned short* src_base = (tid < 128) ? Eh : El;
    const int u = tid & 127;
    const int code_w = u >> 3;
    const int dst_off = ((tid >> 7) << 11) + (code_w << 7)
                      + (((u & 7) << 4) ^ ((code_w & 7) << 4));
    float4 stgA, stgB;
    auto LDP = [&](int i) {
        stgA = *(const float4*)((const char*)src_base + (size_t)(2 * i) * 2048 + (size_t)u * 16);
        stgB = *(const float4*)((const char*)src_base + (size_t)(2 * i + 1) * 2048 + (size_t)u * 16);
    };
    auto STP = [&](int i) {
        *(float4*)&btile[i & 1][0][dst_off] = stgA;
        *(float4*)&btile[i & 1][1][dst_off] = stgB;
    };

    const int cx = (col & 7) << 4;
    const int rb = col << 7;
    const int oh0 = rb + ((g << 4) ^ cx);
    const int oh1 = rb + (((g << 4) + 64) ^ cx);

    float m1_0 = 3.4e38f, m1_1 = 3.4e38f, m1_2 = 3.4e38f, m1_3 = 3.4e38f;
    float m1_4 = 3.4e38f, m1_5 = 3.4e38f, m1_6 = 3.4e38f, m1_7 = 3.4e38f;
    float m2_0 = 3.4e38f, m2_1 = 3.4e38f, m2_2 = 3.4e38f, m2_3 = 3.4e38f;
    float m2_4 = 3.4e38f, m2_5 = 3.4e38f, m2_6 = 3.4e38f, m2_7 = 3.4e38f;
    int i1_0 = 0, i1_1 = 0, i1_2 = 0, i1_3 = 0;
    int i1_4 = 0, i1_5 = 0, i1_6 = 0, i1_7 = 0;

#define TOP2(S, M1, M2, I1, KC)                               \
    {                                                         \
        float t_ = fmaxf((S), M1);                            \
        M2 = fminf(M2, t_);                                   \
        if ((S) < M1) I1 = (KC);                              \
        M1 = fminf(M1, (S));                                  \
    }

#define COMPUTE_TILE(T, BP)                                                  \
    {                                                                        \
        const unsigned char* bp_ = (BP);                                     \
        const bf16x8 Bh0 = *(const bf16x8*)(bp_ + oh0);                      \
        const bf16x8 Bh1 = *(const bf16x8*)(bp_ + oh1);                      \
        const bf16x8 Bl0 = *(const bf16x8*)(bp_ + 2048 + oh0);               \
        const bf16x8 Bl1 = *(const bf16x8*)(bp_ + 2048 + oh1);               \
        const int kc_ = (T) * 16 + col;                                      \
        const float qe_ = esq_lds[kc_];                                      \
        f32x4 a0 = {qe_, qe_, qe_, qe_};                                     \
        f32x4 a1 = {0.f, 0.f, 0.f, 0.f};                                     \
        f32x4 a2 = {0.f, 0.f, 0.f, 0.f};                                     \
        f32x4 c0 = {qe_, qe_, qe_, qe_};                                     \
        f32x4 c1 = {0.f, 0.f, 0.f, 0.f};                                     \
        f32x4 c2 = {0.f, 0.f, 0.f, 0.f};                                     \
        a0 = __builtin_amdgcn_mfma_f32_16x16x32_bf16(A0h0, Bh0, a0, 0, 0, 0);\
        c0 = __builtin_amdgcn_mfma_f32_16x16x32_bf16(A1h0, Bh0, c0, 0, 0, 0);\
        a1 = __builtin_amdgcn_mfma_f32_16x16x32_bf16(A0h0, Bl0, a1, 0, 0, 0);\
        c1 = __builtin_amdgcn_mfma_f32_16x16x32_bf16(A1h0, Bl0, c1, 0, 0, 0);\
        a2 = __builtin_amdgcn_mfma_f32_16x16x32_bf16(A0l0, Bh0, a2, 0, 0, 0);\
        c2 = __builtin_amdgcn_mfma_f32_16x16x32_bf16(A1l0, Bh0, c2, 0, 0, 0);\
        a0 = __builtin_amdgcn_mfma_f32_16x16x32_bf16(A0h1, Bh1, a0, 0, 0, 0);\
        c0 = __builtin_amdgcn_mfma_f32_16x16x32_bf16(A1h1, Bh1, c0, 0, 0, 0);\
        a1 = __builtin_amdgcn_mfma_f32_16x16x32_bf16(A0h1, Bl1, a1, 0, 0, 0);\
        c1 = __builtin_amdgcn_mfma_f32_16x16x32_bf16(A1h1, Bl1, c1, 0, 0, 0);\
        a2 = __builtin_amdgcn_mfma_f32_16x16x32_bf16(A0l1, Bh1, a2, 0, 0, 0);\
        c2 = __builtin_amdgcn_mfma_f32_16x16x32_bf16(A1l1, Bh1, c2, 0, 0, 0);\
        {                                                                    \
            float s0_ = (a0[0] + a1[0]) + a2[0];                             \
            TOP2(s0_, m1_0, m2_0, i1_0, kc_)                                 \
            float s1_ = (a0[1] + a1[1]) + a2[1];                             \
            TOP2(s1_, m1_1, m2_1, i1_1, kc_)                                 \
            float s2_ = (a0[2] + a1[2]) + a2[2];                             \
            TOP2(s2_, m1_2, m2_2, i1_2, kc_)                                 \
            float s3_ = (a0[3] + a1[3]) + a2[3];                             \
            TOP2(s3_, m1_3, m2_3, i1_3, kc_)                                 \
            float s4_ = (c0[0] + c1[0]) + c2[0];                             \
            TOP2(s4_, m1_4, m2_4, i1_4, kc_)                                 \
            float s5_ = (c0[1] + c1[1]) + c2[1];                             \
            TOP2(s5_, m1_5, m2_5, i1_5, kc_)                                 \
            float s6_ = (c0[2] + c1[2]) + c2[2];                             \
            TOP2(s6_, m1_6, m2_6, i1_6, kc_)                                 \
            float s7_ = (c0[3] + c1[3]) + c2[3];                             \
            TOP2(s7_, m1_7, m2_7, i1_7, kc_)                                 \
        }                                                                    \
    }

    LDP(0); STP(0);    // pair 0 staged (vmcnt auto before ds_write)
    LDP(1);            // pair 1 in flight
    __syncthreads();

#pragma unroll 1
    for (int i = 0; i < NPAIR; ++i) {
        if (i + 1 < NPAIR) STP(i + 1);
        if (i + 2 < NPAIR) LDP(i + 2);
        COMPUTE_TILE(2 * i,     &btile[i & 1][0][0])
        COMPUTE_TILE(2 * i + 1, &btile[i & 1][1][0])
        __syncthreads();
    }
#undef COMPUTE_TILE
#undef TOP2

    // cross-lane merge over the 16 lanes of group g; write idx/out + LDS flag
#define MERGE(M1, M2, I1, R, SETOFF)                                           \
    {                                                                          \
        float a1_ = M1, a2_ = M2; int j1 = I1;                                 \
        _Pragma("unroll")                                                      \
        for (int off = 1; off < 16; off <<= 1) {                               \
            float b1 = __shfl_xor(a1_, off);                                   \
            int jb = __shfl_xor(j1, off);                                      \
            float b2 = __shfl_xor(a2_, off);                                   \
            float hi = fmaxf(a1_, b1);                                         \
            a2_ = fminf(fminf(a2_, b2), hi);                                   \
            if (b1 < a1_) j1 = jb;                                             \
            a1_ = fminf(a1_, b1);                                              \
        }                                                                      \
        if (col == 0) {                                                        \
            int pxl = (SETOFF) + w * 16 + g * 4 + (R);                         \
            sflag[pxl] = (a2_ <= a1_ + MARGIN) ? 1 : 0;                        \
            int px = pxbase + pxl;                                             \
            idx[px] = j1;                                                      \
            out[IDX_OFF + px] = (float)j1;                                     \
        }                                                                      \
    }
    MERGE(m1_0, m2_0, i1_0, 0, 0)
    MERGE(m1_1, m2_1, i1_1, 1, 0)
    MERGE(m1_2, m2_2, i1_2, 2, 0)
    MERGE(m1_3, m2_3, i1_3, 3, 0)
    MERGE(m1_4, m2_4, i1_4, 0, 64)
    MERGE(m1_5, m2_5, i1_5, 1, 64)
    MERGE(m1_6, m2_6, i1_6, 2, 64)
    MERGE(m1_7, m2_7, i1_7, 3, 64)
#undef MERGE

    // fused compaction: waves 0,1 ballot the 128 flags, one atomicAdd per wave
    __syncthreads();
    if (tid < PXB) {
        const bool f = sflag[tid] != 0;
        unsigned long long m = __ballot(f);
        int base = 0;
        if (l == 0 && m) base = atomicAdd(count, __popcll(m));
        base = __shfl(base, 0);
        if (f) {
            unsigned long long below = m & ((1ULL << l) - 1ULL);
            list[base + __popcll(below)] = pxbase + tid;
        }
    }
}

// ---------------- cleanup v3 (R17-validated): exact argmin, e tiled via LDS ----------------
__global__ void __launch_bounds__(256, 4) cleanup_kernel(const float* __restrict__ x,
                                                         const float* __restrict__ e,
                                                         const float* __restrict__ esq,
                                                         const int* __restrict__ count,
                                                         const int* __restrict__ list,
                                                         int* __restrict__ idx,
                                                         float* __restrict__ out) {
    __shared__ float tile[DDIM][257];   // 65.8KB transpose tile
    __shared__ float xs[NB][68];
    __shared__ float xsqs[NB];
    __shared__ float rbest[4];
    __shared__ int   ridx[4];
    __shared__ int   plist[NB];

    const int tid = threadIdx.x;
    const int cnt = *count;
    const int nchunk = (cnt + NB - 1) / NB;

    for (int chunk = blockIdx.x; chunk < nchunk; chunk += gridDim.x) {
        const int base = chunk * NB;
        const int np = min(NB, cnt - base);      // block-uniform

        if (tid < np) plist[tid] = list[base + tid];
        __syncthreads();
        for (int q = tid; q < np * 64; q += 256) {
            const int pp = q >> 6, d = q & 63;
            const int p = plist[pp];
            xs[pp][d] = x[(size_t)(p >> 10) * 65536 + (size_t)d * 1024 + (p & 1023)];
        }
        __syncthreads();
        if (tid < np) {
#pragma clang fp contract(off)
            float r[8];
#pragma unroll
            for (int j = 0; j < 8; ++j) { float v = xs[tid][j]; r[j] = v * v; }
#pragma unroll
            for (int ii = 1; ii < 8; ++ii) {
#pragma unroll
                for (int j = 0; j < 8; ++j) { float v = xs[tid][ii * 8 + j]; r[j] += v * v; }
            }
            xsqs[tid] = ((r[0] + r[1]) + (r[2] + r[3])) + ((r[4] + r[5]) + (r[6] + r[7]));
        }

        float best[NB];
        int bidx[NB];
#pragma unroll
        for (int pp = 0; pp < NB; ++pp) { best[pp] = 3.4e38f; bidx[pp] = 0; }

#pragma unroll 1
        for (int T = 0; T < 4; ++T) {
            __syncthreads();
#pragma unroll
            for (int i = 0; i < 16; ++i) {
                const float4 v = *(const float4*)(e + (size_t)T * 16384 + (size_t)i * 1024 + tid * 4);
                const int c = 16 * i + (tid >> 4);
                const int d0 = (4 * tid) & 63;
                tile[d0 + 0][c] = v.x;
                tile[d0 + 1][c] = v.y;
                tile[d0 + 2][c] = v.z;
                tile[d0 + 3][c] = v.w;
            }
            __syncthreads();
            const float qe = esq[T * 256 + tid];
            const int kk = T * 256 + tid;
#pragma unroll
            for (int pp = 0; pp < NB; ++pp) {
                if (pp < np) {
                    float dt = 0.f;
#pragma unroll
                    for (int d = 0; d < DDIM; ++d)
                        dt = __builtin_fmaf(xs[pp][d], tile[d][tid], dt);
                    const float s = (xsqs[pp] - 2.0f * dt) + qe;
                    if (s < best[pp]) { best[pp] = s; bidx[pp] = kk; }
                }
            }
        }

#pragma unroll
        for (int pp = 0; pp < NB; ++pp) {
            if (pp < np) {
                float bb = best[pp];
                int bj = bidx[pp];
#pragma unroll
                for (int off = 1; off < 64; off <<= 1) {
                    float b2 = __shfl_xor(bb, off);
                    int k2 = __shfl_xor(bj, off);
                    if (b2 < bb || (b2 == bb && k2 < bj)) { bb = b2; bj = k2; }
                }
                if ((tid & 63) == 0) { rbest[tid >> 6] = bb; ridx[tid >> 6] = bj; }
                __syncthreads();
                if (tid == 0) {
                    float b0 = rbest[0]; int j0 = ridx[0];
#pragma unroll
                    for (int c2 = 1; c2 < 4; ++c2)
                        if (rbest[c2] < b0 || (rbest[c2] == b0 && ridx[c2] < j0)) {
                            b0 = rbest[c2]; j0 = ridx[c2];
                        }
                    const int p = plist[pp];
                    idx[p] = j0;
                    out[IDX_OFF + p] = (float)j0;
                }
                __syncthreads();
            }
        }
        __syncthreads();
    }
}

// ---------------- gather + transpose + per-block loss partials ----------------
__global__ void __launch_bounds__(256) gather_kernel(const float* __restrict__ x,
                                                     const float* __restrict__ e,
                                                     const int* __restrict__ idx,
                                                     float* __restrict__ out,
                                                     float* __restrict__ partial) {
    const int bd = blockIdx.x;          // = b*64 + d
    const int b = bd >> 6;
    const int d = bd & 63;
    const size_t base = (size_t)bd * 1024;
    const int* idxb = idx + b * 1024;

    float acc = 0.f;
#pragma unroll
    for (int j = 0; j < 4; ++j) {
        int p = threadIdx.x + j * 256;
        int k = idxb[p];
        float ev = e[k * 64 + d];
        float xv = x[base + p];
        out[1 + base + p] = ev;
        float df = ev - xv;
        acc = __builtin_fmaf(df, df, acc);
    }
    __shared__ float sm[256];
    sm[threadIdx.x] = acc;
    __syncthreads();
    for (int s = 128; s > 0; s >>= 1) {
        if (threadIdx.x < s) sm[threadIdx.x] += sm[threadIdx.x + s];
        __syncthreads();
    }
    if (threadIdx.x == 0) partial[bd] = sm[0];
}

__global__ void __launch_bounds__(256) loss_kernel(const float* __restrict__ partial,
                                                   float* __restrict__ out) {
    float acc = 0.f;
    for (int i = threadIdx.x; i < 4096; i += 256) acc += partial[i];
    __shared__ float sm[256];
    sm[threadIdx.x] = acc;
    __syncthreads();
    for (int s = 128; s > 0; s >>= 1) {
        if (threadIdx.x < s) sm[threadIdx.x] += sm[threadIdx.x + s];
        __syncthreads();
    }
    if (threadIdx.x == 0) out[0] = sm[0] * (1.25f / 4194304.f);
}

extern "C" void kernel_launch(void* const* d_in, const int* in_sizes, int n_in,
                              void* d_out, int out_size, void* d_ws, size_t ws_size,
                              hipStream_t stream) {
    const float* x = (const float*)d_in[0];   // [64,64,32,32]
    const float* e = (const float*)d_in[1];   // [1024,64]
    float* out = (float*)d_out;

    // ws: esq 4KB | Eh 128KB | El 128KB | idx 256KB | partial 16KB | count 4KB | list 256KB
    char* wsb = (char*)d_ws;
    float*          esq     = (float*)wsb;
    unsigned short* Eh      = (unsigned short*)(wsb + 4096);
    unsigned short* El      = (unsigned short*)(wsb + 4096 + 131072);
    int*            idx     = (int*)(wsb + 4096 + 2 * 131072);
    float*          partial = (float*)(wsb + 4096 + 2 * 131072 + NPIX * 4);
    int*            count   = (int*)(wsb + 4096 + 2 * 131072 + NPIX * 4 + 16384);
    int*            list    = (int*)(wsb + 4096 + 2 * 131072 + NPIX * 4 + 16384 + 4096);

    esplit_kernel<<<4, 256, 0, stream>>>(e, esq, Eh, El, count);
    gemm_kernel<<<NPIX / PXB, 256, 0, stream>>>(x, Eh, El, esq, count, list, idx, out);
    cleanup_kernel<<<512, 256, 0, stream>>>(x, e, esq, count, list, idx, out);
    gather_kernel<<<4096, 256, 0, stream>>>(x, e, idx, out, partial);
    loss_kernel<<<1, 256, 0, stream>>>(partial, out);
}